// Round 3
// baseline (456.569 us; speedup 1.0000x reference)
//
#include <hip/hip_runtime.h>
#include <cstddef>

// D,H,W,C = 10,200,176,64; convs: (s2,p1) -> (s1,p(0,1,1)) -> (s2,p1)
// Activations channels-last fp16: [d][h(+1 halo)][w(+1 halo)][ci], pixel=128B.
#define HH 200
#define WW 176
#define HP 202
#define WP 178
#define D_IN 10
#define D1 5
#define D2 3
#define D3 2
#define SLICE ((size_t)HP * WP * 64)

typedef _Float16 h8 __attribute__((ext_vector_type(8)));
typedef float f4 __attribute__((ext_vector_type(4)));

// ---------------- weight transform: OIDHW fp32 -> [tap][co][ci] fp16 -------
__global__ __launch_bounds__(256) void wtrans_k(const float* __restrict__ src,
                                                _Float16* __restrict__ dst) {
    int idx = blockIdx.x * 256 + threadIdx.x;
    if (idx >= 27 * 64 * 64) return;
    int i = idx & 63;            // ci (contiguous in dst)
    int o = (idx >> 6) & 63;     // co
    int tap = idx >> 12;         // kd*9 + kh*3 + kw
    dst[idx] = (_Float16)src[(o * 64 + i) * 27 + tap];
}

// ---------------- scatter, last-write-wins (np .at[].set semantics) --------
__global__ __launch_bounds__(256) void winner_k(const int* __restrict__ coors,
                                                int* __restrict__ winner, int nvox) {
    int v = blockIdx.x * 256 + threadIdx.x;
    if (v >= nvox) return;
    int d = coors[v * 4 + 1], h = coors[v * 4 + 2], w = coors[v * 4 + 3];
    atomicMax(&winner[(d * HH + h) * WW + w], v + 1);
}

__global__ __launch_bounds__(256) void scatter_k(const float* __restrict__ feat,
                                                 const int* __restrict__ coors,
                                                 const int* __restrict__ winner,
                                                 _Float16* __restrict__ A, int nvox) {
    int v = blockIdx.x * 4 + (threadIdx.x >> 6);
    int ci = threadIdx.x & 63;
    if (v >= nvox) return;
    int d = coors[v * 4 + 1], h = coors[v * 4 + 2], w = coors[v * 4 + 3];
    if (winner[(d * HH + h) * WW + w] != v + 1) return;
    A[((size_t)d * SLICE) + ((size_t)(h + 1) * WP + (w + 1)) * 64 + ci] = (_Float16)feat[v * 64 + ci];
}

// ---------------- zero halos of A2 and A3 (interiors fully overwritten) ----
__global__ __launch_bounds__(256) void halo_k(_Float16* __restrict__ A2,
                                              _Float16* __restrict__ A3) {
    const int s = blockIdx.x;  // 0..4 -> A2 slice, 5..7 -> A3 slice
    _Float16* base = (s < D1) ? (A2 + (size_t)s * SLICE) : (A3 + (size_t)(s - D1) * SLICE);
    const h8 z = {};
    // per slice: 2 full rows (2*1424 h8) + 2 cols over 202 rows (3232 h8) = 6080 h8
    for (int t = threadIdx.x; t < 6080; t += 256) {
        size_t off;
        if (t < 2848) {
            int r = t / 1424, c = t - r * 1424;
            off = (size_t)(r ? (HP - 1) : 0) * WP * 64 + (size_t)c * 8;
        } else {
            int u = t - 2848;
            int c = u / 1616, v = u - c * 1616;
            int hr = v >> 3, o = v & 7;
            off = ((size_t)hr * WP + (c ? (WP - 1) : 0)) * 64 + (size_t)o * 8;
        }
        *(h8*)(base + off) = z;
    }
}

// ---------------- MFMA implicit-GEMM conv, fused scale+bias+relu -----------
// Wave tile: MT*16 pixels (one h row) x 64 co. Depth-1 register pipeline over
// 18 (tap,chunk) steps per z-slice. launch_bounds(256,3): VGPR cap 170 =
// cur+nxt frag double-buffer (64) + acc (<=64) + addressing.
// mfma_f32_16x16x32_f16: A[m=lane&15][k=quad*8+j], D: co=lane&15, pix=quad*4+reg
template <int MT, int FINAL>
__global__ __launch_bounds__(256, 3) void conv_mfma_k(
    const _Float16* __restrict__ in, void* __restrict__ outp,
    const _Float16* __restrict__ wt,
    const float* __restrict__ scale, const float* __restrict__ bias,
    int inD, int strideD, int padD) {
    const int lane = threadIdx.x & 63;
    const int wave = threadIdx.x >> 6;
    const int l16 = lane & 15;
    const int quad = lane >> 4;
    const int h = blockIdx.y * 4 + wave;   // one h row per wave
    const int wb = blockIdx.x * (MT * 16);
    const int d = blockIdx.z;

    f4 acc[MT][4];
#pragma unroll
    for (int mt = 0; mt < MT; ++mt)
#pragma unroll
        for (int nt = 0; nt < 4; ++nt) acc[mt][nt] = (f4){0.f, 0.f, 0.f, 0.f};

    const int fragoff = l16 * 64 + quad * 8;

#pragma unroll
    for (int kd = 0; kd < 3; ++kd) {
        const int zd = d * strideD + kd - padD;
        if (zd < 0 || zd >= inD) continue;  // wave-uniform
        const _Float16* __restrict__ aplane = in + (size_t)zd * SLICE;
        const _Float16* __restrict__ wbase = wt + (size_t)kd * 9 * 4096 + fragoff;

        h8 a_cur[MT], b_cur[4], a_nxt[MT], b_nxt[4];

        auto loadA = [&](int s, h8* dst) {
            const int tap = s >> 1, chunk = s & 1;
            const int kh = tap / 3, kw = tap - 3 * (tap / 3);
            const _Float16* __restrict__ arow =
                aplane + ((size_t)(h + kh) * WP + (wb + kw)) * 64 + fragoff + chunk * 32;
#pragma unroll
            for (int mt = 0; mt < MT; ++mt) dst[mt] = *(const h8*)(arow + mt * 1024);
        };
        auto loadB = [&](int s, h8* dst) {
            const int tap = s >> 1, chunk = s & 1;
            const _Float16* __restrict__ brow = wbase + tap * 4096 + chunk * 32;
#pragma unroll
            for (int nt = 0; nt < 4; ++nt) dst[nt] = *(const h8*)(brow + nt * 1024);
        };

        loadA(0, a_cur);
        loadB(0, b_cur);
#pragma unroll
        for (int s = 0; s < 18; ++s) {
            if (s < 17) { loadA(s + 1, a_nxt); loadB(s + 1, b_nxt); }
#pragma unroll
            for (int mt = 0; mt < MT; ++mt)
#pragma unroll
                for (int nt = 0; nt < 4; ++nt)
                    acc[mt][nt] = __builtin_amdgcn_mfma_f32_16x16x32_f16(
                        a_cur[mt], b_cur[nt], acc[mt][nt], 0, 0, 0);
            if (s < 17) {
#pragma unroll
                for (int mt = 0; mt < MT; ++mt) a_cur[mt] = a_nxt[mt];
#pragma unroll
                for (int nt = 0; nt < 4; ++nt) b_cur[nt] = b_nxt[nt];
            }
        }
    }

    // epilogue: scale+bias+relu; D layout: co=l16(+nt*16), pixel=mt*16+quad*4+reg
#pragma unroll
    for (int nt = 0; nt < 4; ++nt) {
        const int co = nt * 16 + l16;
        const float s = scale[co];
        const float bb = bias[co];
#pragma unroll
        for (int mt = 0; mt < MT; ++mt) {
#pragma unroll
            for (int r = 0; r < 4; ++r) {
                const int w = wb + mt * 16 + quad * 4 + r;
                if (w < WW) {
                    float v = acc[mt][nt][r] * s + bb;
                    v = v > 0.f ? v : 0.f;
                    if (FINAL) {
                        ((float*)outp)[(((size_t)d * HH + h) * WW + w) * 64 + co] = v;
                    } else {
                        ((_Float16*)outp)[(size_t)d * SLICE + ((size_t)(h + 1) * WP + (w + 1)) * 64 + co] =
                            (_Float16)v;
                    }
                }
            }
        }
    }
}

// ---------------- final transpose: O[d][h][w][co] -> out[(co*2+d)][h][w] ---
__global__ __launch_bounds__(256) void transpose_k(const float* __restrict__ O,
                                                   float* __restrict__ out) {
    __shared__ float tile[64][65];
    const int wb = blockIdx.x * 64;
    const int h = blockIdx.y;
    const int d = blockIdx.z;
    const int t = threadIdx.x;
    {
        const int co = t & 63;
        const int wl = t >> 6;
#pragma unroll
        for (int p = 0; p < 16; ++p) {
            const int w = wb + wl + p * 4;
            float v = 0.f;
            if (w < WW) v = O[(((size_t)d * HH + h) * WW + w) * 64 + co];
            tile[wl + p * 4][co] = v;
        }
    }
    __syncthreads();
    {
        const int wl = t & 63;
        const int cl = t >> 6;
        const int w = wb + wl;
        if (w < WW) {
#pragma unroll
            for (int p = 0; p < 16; ++p) {
                const int co = cl + p * 4;
                out[(((size_t)(co * 2 + d)) * HH + h) * WW + w] = tile[wl][co];
            }
        }
    }
}

// ---------------- launch ---------------------------------------------------
extern "C" void kernel_launch(void* const* d_in, const int* in_sizes, int n_in,
                              void* d_out, int out_size, void* d_ws, size_t ws_size,
                              hipStream_t stream) {
    const float* feat   = (const float*)d_in[0];
    const int*   coors  = (const int*)d_in[1];
    const float* W1     = (const float*)d_in[3];
    const float* scale1 = (const float*)d_in[4];
    const float* bias1  = (const float*)d_in[5];
    const float* W2     = (const float*)d_in[6];
    const float* scale2 = (const float*)d_in[7];
    const float* bias2  = (const float*)d_in[8];
    const float* W3     = (const float*)d_in[9];
    const float* scale3 = (const float*)d_in[10];
    const float* bias3  = (const float*)d_in[11];
    const int nvox = in_sizes[0] / 64;

    // workspace layout: [A1][win][A2][A3][O][wt1..3]; memset covers A1+win only
    const size_t nA1 = (size_t)D_IN * SLICE;   // fp16 elems
    const size_t nWin = (size_t)D_IN * HH * WW;  // ints
    const size_t nA2 = (size_t)D1 * SLICE;
    const size_t nA3 = (size_t)D2 * SLICE;
    const size_t nO = (size_t)D3 * HH * WW * 64;  // fp32 elems
    const size_t nWT = (size_t)27 * 64 * 64;      // fp16 elems

    _Float16* A1 = (_Float16*)d_ws;
    int* win = (int*)(A1 + nA1);
    _Float16* A2 = (_Float16*)(win + nWin);
    _Float16* A3 = A2 + nA2;
    float* O = (float*)(A3 + nA3);
    _Float16* wt1 = (_Float16*)(O + nO);
    _Float16* wt2 = wt1 + nWT;
    _Float16* wt3 = wt2 + nWT;

    hipMemsetAsync(d_ws, 0, nA1 * sizeof(_Float16) + nWin * sizeof(int), stream);
    halo_k<<<dim3(D1 + D2), 256, 0, stream>>>(A2, A3);

    const int nwt_blk = (27 * 64 * 64 + 255) / 256;
    wtrans_k<<<nwt_blk, 256, 0, stream>>>(W1, wt1);
    wtrans_k<<<nwt_blk, 256, 0, stream>>>(W2, wt2);
    wtrans_k<<<nwt_blk, 256, 0, stream>>>(W3, wt3);

    winner_k<<<(nvox + 255) / 256, 256, 0, stream>>>(coors, win, nvox);
    scatter_k<<<(nvox + 3) / 4, 256, 0, stream>>>(feat, coors, win, A1, nvox);

    dim3 blk(256);
    // conv1: A1(d=10) -> A2(d=5), stride 2, pad 1   (3000 waves)
    conv_mfma_k<4, 0><<<dim3(3, 50, D1), blk, 0, stream>>>(A1, A2, wt1, scale1, bias1, D_IN, 2, 1);
    // conv2: A2(5) -> A3(3), stride 1, pad 0(d) 1(h,w)   (1800 waves)
    conv_mfma_k<4, 0><<<dim3(3, 50, D2), blk, 0, stream>>>(A2, A3, wt2, scale2, bias2, D1, 1, 0);
    // conv3: A3(3) -> O(2) channels-last fp32, stride 2, pad 1; MT=2 -> 2400 waves
    conv_mfma_k<2, 1><<<dim3(6, 50, D3), blk, 0, stream>>>(A3, O, wt3, scale3, bias3, D2, 2, 1);

    // O[d][h][w][co] -> out[(co*2+d)][h][w]
    transpose_k<<<dim3(3, HH, D3), blk, 0, stream>>>(O, (float*)d_out);
}

// Round 4
// 301.093 us; speedup vs baseline: 1.5164x; 1.5164x over previous
//
#include <hip/hip_runtime.h>
#include <cstddef>

// D,H,W,C = 10,200,176,64; convs: (s2,p1) -> (s1,p(0,1,1)) -> (s2,p1)
// Activations channels-last fp16: [d][h(+1 halo)][w(+1 halo)][ci], pixel=128B.
#define HH 200
#define WW 176
#define HP 202
#define WP 178
#define D_IN 10
#define D1 5
#define D2 3
#define D3 2
#define SLICE ((size_t)HP * WP * 64)

typedef _Float16 h8 __attribute__((ext_vector_type(8)));
typedef float f4 __attribute__((ext_vector_type(4)));

// ---------------- weight transform: OIDHW fp32 -> [tap][co][ci] fp16 -------
__global__ __launch_bounds__(256) void wtrans_k(const float* __restrict__ src,
                                                _Float16* __restrict__ dst) {
    int idx = blockIdx.x * 256 + threadIdx.x;
    if (idx >= 27 * 64 * 64) return;
    int i = idx & 63;            // ci (contiguous in dst)
    int o = (idx >> 6) & 63;     // co
    int tap = idx >> 12;         // kd*9 + kh*3 + kw
    dst[idx] = (_Float16)src[(o * 64 + i) * 27 + tap];
}

// ---------------- scatter, last-write-wins (np .at[].set semantics) --------
__global__ __launch_bounds__(256) void winner_k(const int* __restrict__ coors,
                                                int* __restrict__ winner, int nvox) {
    int v = blockIdx.x * 256 + threadIdx.x;
    if (v >= nvox) return;
    int d = coors[v * 4 + 1], h = coors[v * 4 + 2], w = coors[v * 4 + 3];
    atomicMax(&winner[(d * HH + h) * WW + w], v + 1);
}

__global__ __launch_bounds__(256) void scatter_k(const float* __restrict__ feat,
                                                 const int* __restrict__ coors,
                                                 const int* __restrict__ winner,
                                                 _Float16* __restrict__ A, int nvox) {
    int v = blockIdx.x * 4 + (threadIdx.x >> 6);
    int ci = threadIdx.x & 63;
    if (v >= nvox) return;
    int d = coors[v * 4 + 1], h = coors[v * 4 + 2], w = coors[v * 4 + 3];
    if (winner[(d * HH + h) * WW + w] != v + 1) return;
    A[((size_t)d * SLICE) + ((size_t)(h + 1) * WP + (w + 1)) * 64 + ci] = (_Float16)feat[v * 64 + ci];
}

// ---------------- zero halos of A2 and A3 (interiors fully overwritten) ----
__global__ __launch_bounds__(256) void halo_k(_Float16* __restrict__ A2,
                                              _Float16* __restrict__ A3) {
    const int s = blockIdx.x;  // 0..4 -> A2 slice, 5..7 -> A3 slice
    _Float16* base = (s < D1) ? (A2 + (size_t)s * SLICE) : (A3 + (size_t)(s - D1) * SLICE);
    const h8 z = {};
    for (int t = threadIdx.x; t < 6080; t += 256) {
        size_t off;
        if (t < 2848) {
            int r = t / 1424, c = t - r * 1424;
            off = (size_t)(r ? (HP - 1) : 0) * WP * 64 + (size_t)c * 8;
        } else {
            int u = t - 2848;
            int c = u / 1616, v = u - c * 1616;
            int hr = v >> 3, o = v & 7;
            off = ((size_t)hr * WP + (c ? (WP - 1) : 0)) * 64 + (size_t)o * 8;
        }
        *(h8*)(base + off) = z;
    }
}

// ---------------- MFMA implicit-GEMM conv with LDS-staged tiles ------------
// Block = 4 waves: wave i computes output row h0+i, MT*16 px, 64 co.
// LDS pixel stride padded to 136 B (34 dwords = 2 mod 32 banks -> 2-way = free).
// Per kd: stage A (6 rows x (MT*16+2) px). Per (kd,kh): stage B (3 taps).
// mfma_f32_16x16x32_f16: A[m=lane&15][k=quad*8+j], D: co=lane&15, pix=quad*4+reg
template <int MT, int FINAL>
__global__ __launch_bounds__(256, 2) void conv_mfma_k(
    const _Float16* __restrict__ in, void* __restrict__ outp,
    const _Float16* __restrict__ wt,
    const float* __restrict__ scale, const float* __restrict__ bias,
    int inD, int strideD, int padD) {
    constexpr int PX = MT * 16 + 2;          // staged pixels per row
    __shared__ _Float16 la[6 * PX * 68];     // 68 fp16 = 136 B per pixel
    __shared__ _Float16 lb[3 * 64 * 68];     // [kw][co][ci(64)+pad]

    const int lane = threadIdx.x & 63;
    const int wave = threadIdx.x >> 6;
    const int l16 = lane & 15;
    const int quad = lane >> 4;
    const int h0 = blockIdx.y * 4;
    const int wb = blockIdx.x * (MT * 16);
    const int d = blockIdx.z;

    f4 acc[MT][4];
#pragma unroll
    for (int mt = 0; mt < MT; ++mt)
#pragma unroll
        for (int nt = 0; nt < 4; ++nt) acc[mt][nt] = (f4){0.f, 0.f, 0.f, 0.f};

    for (int kd = 0; kd < 3; ++kd) {
        const int zd = d * strideD + kd - padD;
        if (zd < 0 || zd >= inD) continue;  // block-uniform
        const _Float16* __restrict__ aplane = in + (size_t)zd * SLICE;

        for (int kh = 0; kh < 3; ++kh) {
            __syncthreads();  // previous phase's reads done before overwrite
            if (kh == 0) {
                // stage A: 6 rows x PX px x 8 chunks of 16B
                const int nA = 6 * PX * 8;
                for (int c = threadIdx.x; c < nA; c += 256) {
                    const int r = c / (PX * 8);
                    const int rem = c - r * (PX * 8);
                    const int p = rem >> 3, s = rem & 7;
                    if (wb + p < WP) {
                        h8 v = *(const h8*)(aplane +
                            ((size_t)(h0 + r) * WP + (wb + p)) * 64 + s * 8);
                        *(h8*)(&la[((r * PX) + p) * 68 + s * 8]) = v;
                    }
                }
            }
            {   // stage B: 3 taps (kw) x 64 co x 8 chunks
                const _Float16* __restrict__ wrow = wt + (size_t)(kd * 9 + kh * 3) * 4096;
                for (int c = threadIdx.x; c < 3 * 64 * 8; c += 256) {
                    const int kw = c >> 9;
                    const int co = (c >> 3) & 63;
                    const int s = c & 7;
                    h8 v = *(const h8*)(wrow + kw * 4096 + co * 64 + s * 8);
                    *(h8*)(&lb[(kw * 64 + co) * 68 + s * 8]) = v;
                }
            }
            __syncthreads();

            // compute: 6 steps (kw x chunk), 16 MFMA each
#pragma unroll
            for (int kw = 0; kw < 3; ++kw) {
#pragma unroll
                for (int c = 0; c < 2; ++c) {
                    const int sub = (c * 4 + quad) * 8;
                    h8 b[4];
#pragma unroll
                    for (int nt = 0; nt < 4; ++nt)
                        b[nt] = *(const h8*)(&lb[(kw * 64 + nt * 16 + l16) * 68 + sub]);
#pragma unroll
                    for (int mt = 0; mt < MT; ++mt) {
                        h8 a = *(const h8*)(
                            &la[((wave + kh) * PX + mt * 16 + l16 + kw) * 68 + sub]);
#pragma unroll
                        for (int nt = 0; nt < 4; ++nt)
                            acc[mt][nt] = __builtin_amdgcn_mfma_f32_16x16x32_f16(
                                a, b[nt], acc[mt][nt], 0, 0, 0);
                    }
                }
            }
        }
    }

    // epilogue: scale+bias+relu; D layout: co=l16(+nt*16), pixel=mt*16+quad*4+reg
    const int h = h0 + wave;
#pragma unroll
    for (int nt = 0; nt < 4; ++nt) {
        const int co = nt * 16 + l16;
        const float s = scale[co];
        const float bb = bias[co];
#pragma unroll
        for (int mt = 0; mt < MT; ++mt) {
#pragma unroll
            for (int r = 0; r < 4; ++r) {
                const int w = wb + mt * 16 + quad * 4 + r;
                if (w < WW) {
                    float v = acc[mt][nt][r] * s + bb;
                    v = v > 0.f ? v : 0.f;
                    if (FINAL) {
                        ((float*)outp)[(((size_t)d * HH + h) * WW + w) * 64 + co] = v;
                    } else {
                        ((_Float16*)outp)[(size_t)d * SLICE +
                            ((size_t)(h + 1) * WP + (w + 1)) * 64 + co] = (_Float16)v;
                    }
                }
            }
        }
    }
}

// ---------------- final transpose: O[d][h][w][co] -> out[(co*2+d)][h][w] ---
__global__ __launch_bounds__(256) void transpose_k(const float* __restrict__ O,
                                                   float* __restrict__ out) {
    __shared__ float tile[64][65];
    const int wb = blockIdx.x * 64;
    const int h = blockIdx.y;
    const int d = blockIdx.z;
    const int t = threadIdx.x;
    {
        const int co = t & 63;
        const int wl = t >> 6;
#pragma unroll
        for (int p = 0; p < 16; ++p) {
            const int w = wb + wl + p * 4;
            float v = 0.f;
            if (w < WW) v = O[(((size_t)d * HH + h) * WW + w) * 64 + co];
            tile[wl + p * 4][co] = v;
        }
    }
    __syncthreads();
    {
        const int wl = t & 63;
        const int cl = t >> 6;
        const int w = wb + wl;
        if (w < WW) {
#pragma unroll
            for (int p = 0; p < 16; ++p) {
                const int co = cl + p * 4;
                out[(((size_t)(co * 2 + d)) * HH + h) * WW + w] = tile[wl][co];
            }
        }
    }
}

// ---------------- launch ---------------------------------------------------
extern "C" void kernel_launch(void* const* d_in, const int* in_sizes, int n_in,
                              void* d_out, int out_size, void* d_ws, size_t ws_size,
                              hipStream_t stream) {
    const float* feat   = (const float*)d_in[0];
    const int*   coors  = (const int*)d_in[1];
    const float* W1     = (const float*)d_in[3];
    const float* scale1 = (const float*)d_in[4];
    const float* bias1  = (const float*)d_in[5];
    const float* W2     = (const float*)d_in[6];
    const float* scale2 = (const float*)d_in[7];
    const float* bias2  = (const float*)d_in[8];
    const float* W3     = (const float*)d_in[9];
    const float* scale3 = (const float*)d_in[10];
    const float* bias3  = (const float*)d_in[11];
    const int nvox = in_sizes[0] / 64;

    // workspace layout: [A1][win][A2][A3][O][wt1..3]; memset covers A1+win only
    const size_t nA1 = (size_t)D_IN * SLICE;     // fp16 elems
    const size_t nWin = (size_t)D_IN * HH * WW;  // ints
    const size_t nA2 = (size_t)D1 * SLICE;
    const size_t nA3 = (size_t)D2 * SLICE;
    const size_t nO = (size_t)D3 * HH * WW * 64;  // fp32 elems
    const size_t nWT = (size_t)27 * 64 * 64;      // fp16 elems

    _Float16* A1 = (_Float16*)d_ws;
    int* win = (int*)(A1 + nA1);
    _Float16* A2 = (_Float16*)(win + nWin);
    _Float16* A3 = A2 + nA2;
    float* O = (float*)(A3 + nA3);
    _Float16* wt1 = (_Float16*)(O + nO);
    _Float16* wt2 = wt1 + nWT;
    _Float16* wt3 = wt2 + nWT;

    hipMemsetAsync(d_ws, 0, nA1 * sizeof(_Float16) + nWin * sizeof(int), stream);
    halo_k<<<dim3(D1 + D2), 256, 0, stream>>>(A2, A3);

    const int nwt_blk = (27 * 64 * 64 + 255) / 256;
    wtrans_k<<<nwt_blk, 256, 0, stream>>>(W1, wt1);
    wtrans_k<<<nwt_blk, 256, 0, stream>>>(W2, wt2);
    wtrans_k<<<nwt_blk, 256, 0, stream>>>(W3, wt3);

    winner_k<<<(nvox + 255) / 256, 256, 0, stream>>>(coors, win, nvox);
    scatter_k<<<(nvox + 3) / 4, 256, 0, stream>>>(feat, coors, win, A1, nvox);

    dim3 blk(256);
    // conv1: A1(d=10) -> A2(d=5), stride 2, pad 1   (750 blocks, 2/CU LDS cap)
    conv_mfma_k<4, 0><<<dim3(3, 50, D1), blk, 0, stream>>>(A1, A2, wt1, scale1, bias1, D_IN, 2, 1);
    // conv2: A2(5) -> A3(3), stride 1, pad 0(d) 1(h,w)   (450 blocks)
    conv_mfma_k<4, 0><<<dim3(3, 50, D2), blk, 0, stream>>>(A2, A3, wt2, scale2, bias2, D1, 1, 0);
    // conv3: A3(3) -> O(2), stride 2, pad 1; MT=2 -> 600 blocks, 3/CU
    conv_mfma_k<2, 1><<<dim3(6, 50, D3), blk, 0, stream>>>(A3, O, wt3, scale3, bias3, D2, 2, 1);

    // O[d][h][w][co] -> out[(co*2+d)][h][w]
    transpose_k<<<dim3(3, HH, D3), blk, 0, stream>>>(O, (float*)d_out);
}

// Round 5
// 271.158 us; speedup vs baseline: 1.6838x; 1.1104x over previous
//
#include <hip/hip_runtime.h>
#include <cstddef>

// D,H,W,C = 10,200,176,64; convs: (s2,p1) -> (s1,p(0,1,1)) -> (s2,p1)
// Activations channels-last fp16: [d][h(+1 halo)][w(+1 halo)][ci], pixel=128B.
#define HH 200
#define WW 176
#define HP 202
#define WP 178
#define D_IN 10
#define D1 5
#define D2 3
#define D3 2
#define SLICE ((size_t)HP * WP * 64)

typedef _Float16 h8 __attribute__((ext_vector_type(8)));
typedef float f4 __attribute__((ext_vector_type(4)));

// ---------------- weight transform: OIDHW fp32 -> [tap][co][ci] fp16 -------
__global__ __launch_bounds__(256) void wtrans_k(const float* __restrict__ src,
                                                _Float16* __restrict__ dst) {
    int idx = blockIdx.x * 256 + threadIdx.x;
    if (idx >= 27 * 64 * 64) return;
    int i = idx & 63;            // ci (contiguous in dst)
    int o = (idx >> 6) & 63;     // co
    int tap = idx >> 12;         // kd*9 + kh*3 + kw
    dst[idx] = (_Float16)src[(o * 64 + i) * 27 + tap];
}

// ---------------- scatter, last-write-wins (np .at[].set semantics) --------
__global__ __launch_bounds__(256) void winner_k(const int* __restrict__ coors,
                                                int* __restrict__ winner, int nvox) {
    int v = blockIdx.x * 256 + threadIdx.x;
    if (v >= nvox) return;
    int d = coors[v * 4 + 1], h = coors[v * 4 + 2], w = coors[v * 4 + 3];
    atomicMax(&winner[(d * HH + h) * WW + w], v + 1);
}

__global__ __launch_bounds__(256) void scatter_k(const float* __restrict__ feat,
                                                 const int* __restrict__ coors,
                                                 const int* __restrict__ winner,
                                                 _Float16* __restrict__ A, int nvox) {
    int v = blockIdx.x * 4 + (threadIdx.x >> 6);
    int ci = threadIdx.x & 63;
    if (v >= nvox) return;
    int d = coors[v * 4 + 1], h = coors[v * 4 + 2], w = coors[v * 4 + 3];
    if (winner[(d * HH + h) * WW + w] != v + 1) return;
    A[((size_t)d * SLICE) + ((size_t)(h + 1) * WP + (w + 1)) * 64 + ci] = (_Float16)feat[v * 64 + ci];
}

// ---------------- zero halos of A2 and A3 (interiors fully overwritten) ----
__global__ __launch_bounds__(256) void halo_k(_Float16* __restrict__ A2,
                                              _Float16* __restrict__ A3) {
    const int s = blockIdx.x;  // 0..4 -> A2 slice, 5..7 -> A3 slice
    _Float16* base = (s < D1) ? (A2 + (size_t)s * SLICE) : (A3 + (size_t)(s - D1) * SLICE);
    const h8 z = {};
    for (int t = threadIdx.x; t < 6080; t += 256) {
        size_t off;
        if (t < 2848) {
            int r = t / 1424, c = t - r * 1424;
            off = (size_t)(r ? (HP - 1) : 0) * WP * 64 + (size_t)c * 8;
        } else {
            int u = t - 2848;
            int c = u / 1616, v = u - c * 1616;
            int hr = v >> 3, o = v & 7;
            off = ((size_t)hr * WP + (c ? (WP - 1) : 0)) * 64 + (size_t)o * 8;
        }
        *(h8*)(base + off) = z;
    }
}

// ---------------- MFMA implicit-GEMM conv with LDS-staged tiles ------------
// Block = 4 waves: wave i -> output row h0+i, 48 px (MT=3), 64 co.
// LDS budget 51,776 B -> 3 blocks/CU (12 waves): the round-4 fix.
//   la: A-tile 4 rows x 50 px, pixel stride 136 B (2 mod 32 banks: free).
//   lb: B 3 taps x 64 co x 64 ci, unpadded, chunk XOR-swizzled (s^= co&7):
//       reads conflict-free, staging writes 8-way on 24 instrs/phase (cheap).
// Staged per (kd,kh); A re-staged each kh (L2 absorbs the re-fetch).
// mfma_f32_16x16x32_f16: A[m=lane&15][k=quad*8+j], D: co=lane&15, px=quad*4+reg
template <int FINAL>
__global__ __launch_bounds__(256, 3) void conv_mfma_k(
    const _Float16* __restrict__ in, void* __restrict__ outp,
    const _Float16* __restrict__ wt,
    const float* __restrict__ scale, const float* __restrict__ bias,
    int inD, int strideD, int padD) {
    constexpr int MT = 3;
    constexpr int PX = MT * 16 + 2;          // 50 staged pixels per row
    __shared__ _Float16 la[4 * PX * 68];     // 27,200 B
    __shared__ _Float16 lb[3 * 64 * 64];     // 24,576 B

    const int lane = threadIdx.x & 63;
    const int wave = threadIdx.x >> 6;
    const int l16 = lane & 15;
    const int quad = lane >> 4;
    const int h0 = blockIdx.y * 4;
    const int wb = blockIdx.x * (MT * 16);   // 0,48,96,144 (last ragged, masked)
    const int d = blockIdx.z;

    f4 acc[MT][4];
#pragma unroll
    for (int mt = 0; mt < MT; ++mt)
#pragma unroll
        for (int nt = 0; nt < 4; ++nt) acc[mt][nt] = (f4){0.f, 0.f, 0.f, 0.f};

    for (int kd = 0; kd < 3; ++kd) {
        const int zd = d * strideD + kd - padD;
        if (zd < 0 || zd >= inD) continue;  // block-uniform
        const _Float16* __restrict__ aplane = in + (size_t)zd * SLICE;

        for (int kh = 0; kh < 3; ++kh) {
            __syncthreads();  // previous phase's reads done before overwrite
            // stage A: 4 rows (h0+kh+0..3) x PX px x 8 chunks of 16B
            for (int c = threadIdx.x; c < 4 * PX * 8; c += 256) {
                const int r = c / (PX * 8);
                const int rem = c - r * (PX * 8);
                const int p = rem >> 3, s = rem & 7;
                if (wb + p < WP) {
                    h8 v = *(const h8*)(aplane +
                        ((size_t)(h0 + kh + r) * WP + (wb + p)) * 64 + s * 8);
                    *(h8*)(&la[(r * PX + p) * 68 + s * 8]) = v;
                }
            }
            // stage B: 3 taps (kw) x 64 co x 8 chunks, XOR-swizzled
            {
                const _Float16* __restrict__ wrow = wt + (size_t)(kd * 9 + kh * 3) * 4096;
                for (int c = threadIdx.x; c < 3 * 64 * 8; c += 256) {
                    const int kw = c >> 9;
                    const int co = (c >> 3) & 63;
                    const int s = c & 7;
                    h8 v = *(const h8*)(wrow + kw * 4096 + co * 64 + s * 8);
                    *(h8*)(&lb[(kw * 64 + co) * 64 + (s ^ (co & 7)) * 8]) = v;
                }
            }
            __syncthreads();

            // compute: 6 steps (kw x chunk), 12 MFMA each
#pragma unroll
            for (int kw = 0; kw < 3; ++kw) {
#pragma unroll
                for (int c = 0; c < 2; ++c) {
                    const int q = c * 4 + quad;
                    h8 b[4];
#pragma unroll
                    for (int nt = 0; nt < 4; ++nt)   // (nt*16+l16)&7 == l16&7
                        b[nt] = *(const h8*)(&lb[(kw * 64 + nt * 16 + l16) * 64 +
                                                 (q ^ (l16 & 7)) * 8]);
#pragma unroll
                    for (int mt = 0; mt < MT; ++mt) {
                        h8 a = *(const h8*)(
                            &la[(wave * PX + mt * 16 + l16 + kw) * 68 + q * 8]);
#pragma unroll
                        for (int nt = 0; nt < 4; ++nt)
                            acc[mt][nt] = __builtin_amdgcn_mfma_f32_16x16x32_f16(
                                a, b[nt], acc[mt][nt], 0, 0, 0);
                    }
                }
            }
        }
    }

    // epilogue: scale+bias+relu; D layout: co=l16(+nt*16), px=mt*16+quad*4+reg
    const int h = h0 + wave;
#pragma unroll
    for (int nt = 0; nt < 4; ++nt) {
        const int co = nt * 16 + l16;
        const float s = scale[co];
        const float bb = bias[co];
#pragma unroll
        for (int mt = 0; mt < MT; ++mt) {
            const int w0 = wb + mt * 16 + quad * 4;  // w0 % 4 == 0
            if (w0 < WW) {                           // w0+3 <= 175 when true
                if (FINAL) {
                    f4 v;
#pragma unroll
                    for (int r = 0; r < 4; ++r) {
                        float x = acc[mt][nt][r] * s + bb;
                        v[r] = x > 0.f ? x : 0.f;
                    }
                    // out[(co*2+d)][h][w0..w0+3], aligned float4
                    *(f4*)((float*)outp + (((size_t)(co * 2 + d)) * HH + h) * WW + w0) = v;
                } else {
#pragma unroll
                    for (int r = 0; r < 4; ++r) {
                        float x = acc[mt][nt][r] * s + bb;
                        x = x > 0.f ? x : 0.f;
                        ((_Float16*)outp)[(size_t)d * SLICE +
                            ((size_t)(h + 1) * WP + (w0 + r + 1)) * 64 + co] = (_Float16)x;
                    }
                }
            }
        }
    }
}

// ---------------- launch ---------------------------------------------------
extern "C" void kernel_launch(void* const* d_in, const int* in_sizes, int n_in,
                              void* d_out, int out_size, void* d_ws, size_t ws_size,
                              hipStream_t stream) {
    const float* feat   = (const float*)d_in[0];
    const int*   coors  = (const int*)d_in[1];
    const float* W1     = (const float*)d_in[3];
    const float* scale1 = (const float*)d_in[4];
    const float* bias1  = (const float*)d_in[5];
    const float* W2     = (const float*)d_in[6];
    const float* scale2 = (const float*)d_in[7];
    const float* bias2  = (const float*)d_in[8];
    const float* W3     = (const float*)d_in[9];
    const float* scale3 = (const float*)d_in[10];
    const float* bias3  = (const float*)d_in[11];
    const int nvox = in_sizes[0] / 64;

    // workspace layout: [A1][win][A2][A3][wt1..3]; memset covers A1+win only
    const size_t nA1 = (size_t)D_IN * SLICE;     // fp16 elems
    const size_t nWin = (size_t)D_IN * HH * WW;  // ints
    const size_t nA2 = (size_t)D1 * SLICE;
    const size_t nA3 = (size_t)D2 * SLICE;
    const size_t nWT = (size_t)27 * 64 * 64;     // fp16 elems

    _Float16* A1 = (_Float16*)d_ws;
    int* win = (int*)(A1 + nA1);
    _Float16* A2 = (_Float16*)(win + nWin);
    _Float16* A3 = A2 + nA2;
    _Float16* wt1 = A3 + nA3;
    _Float16* wt2 = wt1 + nWT;
    _Float16* wt3 = wt2 + nWT;

    hipMemsetAsync(d_ws, 0, nA1 * sizeof(_Float16) + nWin * sizeof(int), stream);
    halo_k<<<dim3(D1 + D2), 256, 0, stream>>>(A2, A3);

    const int nwt_blk = (27 * 64 * 64 + 255) / 256;
    wtrans_k<<<nwt_blk, 256, 0, stream>>>(W1, wt1);
    wtrans_k<<<nwt_blk, 256, 0, stream>>>(W2, wt2);
    wtrans_k<<<nwt_blk, 256, 0, stream>>>(W3, wt3);

    winner_k<<<(nvox + 255) / 256, 256, 0, stream>>>(coors, win, nvox);
    scatter_k<<<(nvox + 3) / 4, 256, 0, stream>>>(feat, coors, win, A1, nvox);

    dim3 blk(256);
    // conv1: A1(d=10) -> A2(d=5), stride 2, pad 1   (1000 blocks, 3/CU)
    conv_mfma_k<0><<<dim3(4, 50, D1), blk, 0, stream>>>(A1, A2, wt1, scale1, bias1, D_IN, 2, 1);
    // conv2: A2(5) -> A3(3), stride 1, pad 0(d) 1(h,w)   (600 blocks)
    conv_mfma_k<0><<<dim3(4, 50, D2), blk, 0, stream>>>(A2, A3, wt2, scale2, bias2, D1, 1, 0);
    // conv3: A3(3) -> out planar fp32 directly (float4 stores), stride 2, pad 1
    conv_mfma_k<1><<<dim3(4, 50, D3), blk, 0, stream>>>(A3, (float*)d_out, wt3, scale3, bias3, D2, 2, 1);
}

// Round 6
// 219.402 us; speedup vs baseline: 2.0810x; 1.2359x over previous
//
#include <hip/hip_runtime.h>
#include <cstddef>

// D,H,W,C = 10,200,176,64; convs: (s2,p1) -> (s1,p(0,1,1)) -> (s2,p1)
// Activations channels-last fp16, pixel = 128 B, CHUNK-SWIZZLED within pixel:
//   16B chunk s of pixel at column P stored at position s ^ (P & 7).
// This makes a verbatim global_load_lds copy bank-conflict-free for MFMA
// fragment reads (start bank spread, <=2-way = free).
#define HH 200
#define WW 176
#define HP 202
#define WP 178
#define D_IN 10
#define D1 5
#define D2 3
#define D3 2
#define SLICE ((size_t)HP * WP * 64)

#define LDSA_ROW 3200      // h16 per staged tile row (50 px * 64)
#define LDSB_OFF 32256     // h16 offset of B region (64,512 B / 2)
#define LDS_BYTES 138240   // 64,512 (A) + 73,728 (B)

typedef _Float16 h8 __attribute__((ext_vector_type(8)));
typedef float f4 __attribute__((ext_vector_type(4)));

__device__ __forceinline__ void gl_lds16(const void* g, void* l) {
    __builtin_amdgcn_global_load_lds(
        (const __attribute__((address_space(1))) void*)g,
        (__attribute__((address_space(3))) void*)l, 16, 0, 0);
}

// ---------------- weight transform: OIDHW fp32 -> [kd][kh][kw][co][ci swz] --
__global__ __launch_bounds__(256) void wtrans_k(const float* __restrict__ src,
                                                _Float16* __restrict__ dst) {
    int idx = blockIdx.x * 256 + threadIdx.x;
    if (idx >= 27 * 64 * 64) return;
    int ci = idx & 63;
    int co = (idx >> 6) & 63;
    int tap = idx >> 12;                  // kd*9 + kh*3 + kw
    int s = ci >> 3, j = ci & 7;
    dst[tap * 4096 + co * 64 + (((s ^ (co & 7)) << 3) | j)] =
        (_Float16)src[(co * 64 + ci) * 27 + tap];
}

// ---------------- scatter, last-write-wins (np .at[].set semantics) --------
__global__ __launch_bounds__(256) void winner_k(const int* __restrict__ coors,
                                                int* __restrict__ winner, int nvox) {
    int v = blockIdx.x * 256 + threadIdx.x;
    if (v >= nvox) return;
    int d = coors[v * 4 + 1], h = coors[v * 4 + 2], w = coors[v * 4 + 3];
    atomicMax(&winner[(d * HH + h) * WW + w], v + 1);
}

__global__ __launch_bounds__(256) void scatter_k(const float* __restrict__ feat,
                                                 const int* __restrict__ coors,
                                                 const int* __restrict__ winner,
                                                 _Float16* __restrict__ A, int nvox) {
    int v = blockIdx.x * 4 + (threadIdx.x >> 6);
    int ci = threadIdx.x & 63;
    if (v >= nvox) return;
    int d = coors[v * 4 + 1], h = coors[v * 4 + 2], w = coors[v * 4 + 3];
    if (winner[(d * HH + h) * WW + w] != v + 1) return;
    int P = w + 1;
    int swz = (((ci >> 3) ^ (P & 7)) << 3) | (ci & 7);
    A[(size_t)d * SLICE + ((size_t)(h + 1) * WP + P) * 64 + swz] = (_Float16)feat[v * 64 + ci];
}

// ---------------- zero halos of A2 and A3 (interiors fully overwritten) ----
__global__ __launch_bounds__(256) void halo_k(_Float16* __restrict__ A2,
                                              _Float16* __restrict__ A3) {
    const int s = blockIdx.x;  // 0..4 -> A2 slice, 5..7 -> A3 slice
    _Float16* base = (s < D1) ? (A2 + (size_t)s * SLICE) : (A3 + (size_t)(s - D1) * SLICE);
    const h8 z = {};
    for (int t = threadIdx.x; t < 6080; t += 256) {
        size_t off;
        if (t < 2848) {
            int r = t / 1424, c = t - r * 1424;
            off = (size_t)(r ? (HP - 1) : 0) * WP * 64 + (size_t)c * 8;
        } else {
            int u = t - 2848;
            int c = u / 1616, v = u - c * 1616;
            int hr = v >> 3, o = v & 7;
            off = ((size_t)hr * WP + (c ? (WP - 1) : 0)) * 64 + (size_t)o * 8;
        }
        *(h8*)(base + off) = z;
    }
}

// ---------------- MFMA implicit-GEMM conv: 1 big phase per kd --------------
// Block = 512 thr (8 waves); wave i -> output row h0+i, 48 px (MT=3), 64 co.
// Per kd: global_load_lds-stage A (10 rows x 50 px, 64.5 KB) + B (9 taps,
// 73.7 KB), ONE barrier pair, then 18 steps x 12 MFMA per wave (1728/block).
// mfma_f32_16x16x32_f16: A[m=lane&15][k=quad*8+j], D: co=lane&15, px=quad*4+reg
template <int FINAL>
__global__ __launch_bounds__(512, 2) void conv_mfma_k(
    const _Float16* __restrict__ in, void* __restrict__ outp,
    const _Float16* __restrict__ wt,
    const float* __restrict__ scale, const float* __restrict__ bias,
    int inD, int strideD, int padD) {
    extern __shared__ char smem_raw[];
    _Float16* smem = (_Float16*)smem_raw;

    const int lane = threadIdx.x & 63;
    const int wave = threadIdx.x >> 6;   // 0..7
    const int l16 = lane & 15;
    const int quad = lane >> 4;
    const int h0 = blockIdx.y * 8;
    const int wb = blockIdx.x * 48;      // 48 | 8 so (wb+px)&7 == px&7
    const int d = blockIdx.z;

    f4 acc[3][4];
#pragma unroll
    for (int mt = 0; mt < 3; ++mt)
#pragma unroll
        for (int nt = 0; nt < 4; ++nt) acc[mt][nt] = (f4){0.f, 0.f, 0.f, 0.f};

    for (int kd = 0; kd < 3; ++kd) {
        const int zd = d * strideD + kd - padD;
        if (zd < 0 || zd >= inD) continue;  // block-uniform
        const _Float16* __restrict__ aplane = in + (size_t)zd * SLICE;
        const _Float16* __restrict__ wkd = wt + (size_t)kd * 9 * 4096;

        __syncthreads();  // protect previous phase's LDS reads
        // stage: A = 63 wave-instrs (4000 chunks + pad), B = 72 (4608 exact)
        for (int j = wave; j < 135; j += 8) {
            if (j < 63) {
                int c = j * 64 + lane;
                int r = c / 400;
                int rem = c - r * 400;
                if (r > 9) r = 9;                  // overrun chunks: harmless dup
                int px = rem >> 3, s = rem & 7;
                int g = wb + px;
                if (g > 177) g = 177;              // ragged right edge: dup col
                gl_lds16(aplane + ((size_t)(h0 + r) * WP + g) * 64 + s * 8,
                         smem_raw + j * 1024);
            } else {
                int c = (j - 63) * 64 + lane;
                gl_lds16(wkd + c * 8, smem_raw + 64512 + (j - 63) * 1024);
            }
        }
        __syncthreads();  // drains vmcnt: staged data visible

        // compute: 18 steps (kh x kw x K-half), 12 MFMA each per wave
#pragma unroll
        for (int kh = 0; kh < 3; ++kh) {
#pragma unroll
            for (int kw = 0; kw < 3; ++kw) {
#pragma unroll
                for (int ch = 0; ch < 2; ++ch) {
                    const int q = ch * 4 + quad;
                    const int tap = kh * 3 + kw;
                    h8 b[4];
#pragma unroll
                    for (int nt = 0; nt < 4; ++nt)
                        b[nt] = *(const h8*)(smem + LDSB_OFF + tap * 4096 +
                                             (nt * 16 + l16) * 64 + ((q ^ (l16 & 7)) << 3));
#pragma unroll
                    for (int mt = 0; mt < 3; ++mt) {
                        const int px = mt * 16 + l16 + kw;
                        h8 a = *(const h8*)(smem + (wave + kh) * LDSA_ROW +
                                            px * 64 + ((q ^ (px & 7)) << 3));
#pragma unroll
                        for (int nt = 0; nt < 4; ++nt)
                            acc[mt][nt] = __builtin_amdgcn_mfma_f32_16x16x32_f16(
                                a, b[nt], acc[mt][nt], 0, 0, 0);
                    }
                }
            }
        }
    }

    // epilogue: scale+bias+relu; D layout: co=l16(+nt*16), px=mt*16+quad*4+reg
    const int h = h0 + wave;
#pragma unroll
    for (int nt = 0; nt < 4; ++nt) {
        const int co = nt * 16 + l16;
        const float s = scale[co];
        const float bb = bias[co];
#pragma unroll
        for (int mt = 0; mt < 3; ++mt) {
            const int w0 = wb + mt * 16 + quad * 4;  // multiple of 4
            if (w0 < WW) {
                if (FINAL) {
                    f4 v;
#pragma unroll
                    for (int r = 0; r < 4; ++r) {
                        float x = acc[mt][nt][r] * s + bb;
                        v[r] = x > 0.f ? x : 0.f;
                    }
                    *(f4*)((float*)outp + (((size_t)(co * 2 + d)) * HH + h) * WW + w0) = v;
                } else {
#pragma unroll
                    for (int r = 0; r < 4; ++r) {
                        float x = acc[mt][nt][r] * s + bb;
                        x = x > 0.f ? x : 0.f;
                        const int P = w0 + r + 1;
                        const int swz = (((co >> 3) ^ (P & 7)) << 3) | (co & 7);
                        ((_Float16*)outp)[(size_t)d * SLICE +
                            ((size_t)(h + 1) * WP + P) * 64 + swz] = (_Float16)x;
                    }
                }
            }
        }
    }
}

// ---------------- launch ---------------------------------------------------
extern "C" void kernel_launch(void* const* d_in, const int* in_sizes, int n_in,
                              void* d_out, int out_size, void* d_ws, size_t ws_size,
                              hipStream_t stream) {
    const float* feat   = (const float*)d_in[0];
    const int*   coors  = (const int*)d_in[1];
    const float* W1     = (const float*)d_in[3];
    const float* scale1 = (const float*)d_in[4];
    const float* bias1  = (const float*)d_in[5];
    const float* W2     = (const float*)d_in[6];
    const float* scale2 = (const float*)d_in[7];
    const float* bias2  = (const float*)d_in[8];
    const float* W3     = (const float*)d_in[9];
    const float* scale3 = (const float*)d_in[10];
    const float* bias3  = (const float*)d_in[11];
    const int nvox = in_sizes[0] / 64;

    // workspace: [A1][win][A2][A3][wt1..3]; memset covers A1+win only
    const size_t nA1 = (size_t)D_IN * SLICE;     // fp16 elems
    const size_t nWin = (size_t)D_IN * HH * WW;  // ints
    const size_t nA2 = (size_t)D1 * SLICE;
    const size_t nA3 = (size_t)D2 * SLICE;
    const size_t nWT = (size_t)27 * 64 * 64;     // fp16 elems

    _Float16* A1 = (_Float16*)d_ws;
    int* win = (int*)(A1 + nA1);
    _Float16* A2 = (_Float16*)(win + nWin);
    _Float16* A3 = A2 + nA2;
    _Float16* wt1 = A3 + nA3;
    _Float16* wt2 = wt1 + nWT;
    _Float16* wt3 = wt2 + nWT;

    hipFuncSetAttribute((const void*)conv_mfma_k<0>,
                        hipFuncAttributeMaxDynamicSharedMemorySize, LDS_BYTES);
    hipFuncSetAttribute((const void*)conv_mfma_k<1>,
                        hipFuncAttributeMaxDynamicSharedMemorySize, LDS_BYTES);

    hipMemsetAsync(d_ws, 0, nA1 * sizeof(_Float16) + nWin * sizeof(int), stream);
    halo_k<<<dim3(D1 + D2), 256, 0, stream>>>(A2, A3);

    const int nwt_blk = (27 * 64 * 64 + 255) / 256;
    wtrans_k<<<nwt_blk, 256, 0, stream>>>(W1, wt1);
    wtrans_k<<<nwt_blk, 256, 0, stream>>>(W2, wt2);
    wtrans_k<<<nwt_blk, 256, 0, stream>>>(W3, wt3);

    winner_k<<<(nvox + 255) / 256, 256, 0, stream>>>(coors, win, nvox);
    scatter_k<<<(nvox + 3) / 4, 256, 0, stream>>>(feat, coors, win, A1, nvox);

    dim3 blk(512);
    // conv1: A1(10) -> A2(5)  (500 blocks, 1/CU)
    conv_mfma_k<0><<<dim3(4, 25, D1), blk, LDS_BYTES, stream>>>(A1, A2, wt1, scale1, bias1, D_IN, 2, 1);
    // conv2: A2(5) -> A3(3)   (300 blocks)
    conv_mfma_k<0><<<dim3(4, 25, D2), blk, LDS_BYTES, stream>>>(A2, A3, wt2, scale2, bias2, D1, 1, 0);
    // conv3: A3(3) -> out planar fp32 (float4 stores)  (200 blocks)
    conv_mfma_k<1><<<dim3(4, 25, D3), blk, LDS_BYTES, stream>>>(A3, (float*)d_out, wt3, scale3, bias3, D2, 2, 1);
}

// Round 7
// 206.102 us; speedup vs baseline: 2.2153x; 1.0645x over previous
//
#include <hip/hip_runtime.h>
#include <cstddef>

// D,H,W,C = 10,200,176,64; convs: (s2,p1) -> (s1,p(0,1,1)) -> (s2,p1)
// Activations channels-last fp16, pixel = 128 B, CHUNK-SWIZZLED within pixel:
//   16B chunk s of pixel at column P stored at position s ^ (P & 7).
// Verbatim global_load_lds staging then gives conflict-free MFMA fragment reads.
#define HH 200
#define WW 176
#define HP 202
#define WP 178
#define D_IN 10
#define D1 5
#define D2 3
#define D3 2
#define SLICE ((size_t)HP * WP * 64)

// LDS: A-tile 6 rows x 50 px x 128 B = 38,400 (+512 overrun pad), B 3 taps = 24,576.
#define LB_OFF 38912           // byte offset of B region
#define LDS_TOTAL (38912 + 24576)  // 63,488 -> 2 blocks/CU

typedef _Float16 h8 __attribute__((ext_vector_type(8)));
typedef float f4 __attribute__((ext_vector_type(4)));

__device__ __forceinline__ void gl_lds16(const void* g, void* l) {
    __builtin_amdgcn_global_load_lds(
        (const __attribute__((address_space(1))) void*)g,
        (__attribute__((address_space(3))) void*)l, 16, 0, 0);
}

// ------ weight transform (all 3 sets, one launch): OIDHW f32 -> [tap][co][ci swz] f16
__global__ __launch_bounds__(256) void wtrans_k(const float* __restrict__ W1,
                                                const float* __restrict__ W2,
                                                const float* __restrict__ W3,
                                                _Float16* __restrict__ dst) {
    int idx = blockIdx.x * 256 + threadIdx.x;
    if (idx >= 3 * 27 * 64 * 64) return;
    int set = idx / (27 * 64 * 64);
    int r = idx - set * (27 * 64 * 64);
    const float* src = set == 0 ? W1 : (set == 1 ? W2 : W3);
    int ci = r & 63;
    int co = (r >> 6) & 63;
    int tap = r >> 12;                    // kd*9 + kh*3 + kw
    int s = ci >> 3, j = ci & 7;
    dst[set * 110592 + tap * 4096 + co * 64 + (((s ^ (co & 7)) << 3) | j)] =
        (_Float16)src[(co * 64 + ci) * 27 + tap];
}

// ---------------- scatter, last-write-wins (np .at[].set semantics) --------
__global__ __launch_bounds__(256) void winner_k(const int* __restrict__ coors,
                                                int* __restrict__ winner, int nvox) {
    int v = blockIdx.x * 256 + threadIdx.x;
    if (v >= nvox) return;
    int d = coors[v * 4 + 1], h = coors[v * 4 + 2], w = coors[v * 4 + 3];
    atomicMax(&winner[(d * HH + h) * WW + w], v + 1);
}

__global__ __launch_bounds__(256) void scatter_k(const float* __restrict__ feat,
                                                 const int* __restrict__ coors,
                                                 const int* __restrict__ winner,
                                                 _Float16* __restrict__ A, int nvox) {
    int v = blockIdx.x * 4 + (threadIdx.x >> 6);
    int ci = threadIdx.x & 63;
    if (v >= nvox) return;
    int d = coors[v * 4 + 1], h = coors[v * 4 + 2], w = coors[v * 4 + 3];
    if (winner[(d * HH + h) * WW + w] != v + 1) return;
    int P = w + 1;
    int swz = (((ci >> 3) ^ (P & 7)) << 3) | (ci & 7);
    A[(size_t)d * SLICE + ((size_t)(h + 1) * WP + P) * 64 + swz] = (_Float16)feat[v * 64 + ci];
}

// ---------------- zero halos of A2 and A3 (interiors fully overwritten) ----
__global__ __launch_bounds__(256) void halo_k(_Float16* __restrict__ A2,
                                              _Float16* __restrict__ A3) {
    const int s = blockIdx.x;  // 0..4 -> A2 slice, 5..7 -> A3 slice
    _Float16* base = (s < D1) ? (A2 + (size_t)s * SLICE) : (A3 + (size_t)(s - D1) * SLICE);
    const h8 z = {};
    for (int t = threadIdx.x; t < 6080; t += 256) {
        size_t off;
        if (t < 2848) {
            int r = t / 1424, c = t - r * 1424;
            off = (size_t)(r ? (HP - 1) : 0) * WP * 64 + (size_t)c * 8;
        } else {
            int u = t - 2848;
            int c = u / 1616, v = u - c * 1616;
            int hr = v >> 3, o = v & 7;
            off = ((size_t)hr * WP + (c ? (WP - 1) : 0)) * 64 + (size_t)o * 8;
        }
        *(h8*)(base + off) = z;
    }
}

// ---------------- MFMA implicit-GEMM conv: 4-wave blocks, 2 blocks/CU ------
// Wave i -> output row h0+i, 48 px (MT=3), 64 co.
// Per kd: stage A (6 rows x 50 px, glds) once + B per kh (3 taps, glds).
// 2 co-resident blocks overlap each other's barrier drains.
// mfma_f32_16x16x32_f16: A[m=lane&15][k=quad*8+j], D: co=lane&15, px=quad*4+reg
template <int FINAL>
__global__ __launch_bounds__(256, 2) void conv_mfma_k(
    const _Float16* __restrict__ in, void* __restrict__ outp,
    const _Float16* __restrict__ wt,
    const float* __restrict__ scale, const float* __restrict__ bias,
    int inD, int strideD, int padD) {
    __shared__ char smem_raw[LDS_TOTAL];
    _Float16* smem = (_Float16*)smem_raw;

    const int lane = threadIdx.x & 63;
    const int wave = threadIdx.x >> 6;   // 0..3
    const int l16 = lane & 15;
    const int quad = lane >> 4;
    const int h0 = blockIdx.y * 4;
    const int wb = blockIdx.x * 48;      // 48 | 8 so (wb+px)&7 == px&7
    const int d = blockIdx.z;

    f4 acc[3][4];
#pragma unroll
    for (int mt = 0; mt < 3; ++mt)
#pragma unroll
        for (int nt = 0; nt < 4; ++nt) acc[mt][nt] = (f4){0.f, 0.f, 0.f, 0.f};

    for (int kd = 0; kd < 3; ++kd) {
        const int zd = d * strideD + kd - padD;
        if (zd < 0 || zd >= inD) continue;  // block-uniform
        const _Float16* __restrict__ aplane = in + (size_t)zd * SLICE;

        for (int kh = 0; kh < 3; ++kh) {
            __syncthreads();  // previous phase's LDS reads complete
            if (kh == 0) {
                // stage A: 2400 chunks -> 38 wave-instrs (last one pads)
                for (int j = wave; j < 38; j += 4) {
                    int c = j * 64 + lane;
                    int r = c / 400;
                    int rem = c - r * 400;
                    if (r > 5) { r = 5; rem = c - 2000; }  // overrun -> pad region
                    int px = rem >> 3, s = rem & 7;
                    int g = wb + px;
                    if (g > 177) g = 177;                  // ragged edge: dup col
                    gl_lds16(aplane + ((size_t)(h0 + r) * WP + g) * 64 + s * 8,
                             smem_raw + j * 1024);
                }
            }
            {   // stage B: 1536 chunks -> 24 wave-instrs, verbatim (pre-swizzled)
                const _Float16* __restrict__ wrow = wt + (size_t)(kd * 9 + kh * 3) * 4096;
                for (int j = wave; j < 24; j += 4)
                    gl_lds16(wrow + (j * 64 + lane) * 8, smem_raw + LB_OFF + j * 1024);
            }
            __syncthreads();  // drains vmcnt: staged data visible

            // compute: 6 steps (kw x K-half), 12 MFMA each per wave
#pragma unroll
            for (int kw = 0; kw < 3; ++kw) {
#pragma unroll
                for (int ch = 0; ch < 2; ++ch) {
                    const int q = ch * 4 + quad;
                    h8 b[4];
#pragma unroll
                    for (int nt = 0; nt < 4; ++nt)
                        b[nt] = *(const h8*)(smem + (LB_OFF / 2) + (kw * 64 + nt * 16 + l16) * 64 +
                                             ((q ^ (l16 & 7)) << 3));
#pragma unroll
                    for (int mt = 0; mt < 3; ++mt) {
                        const int px = mt * 16 + l16 + kw;
                        h8 a = *(const h8*)(smem + (wave + kh) * 3200 +
                                            px * 64 + ((q ^ (px & 7)) << 3));
#pragma unroll
                        for (int nt = 0; nt < 4; ++nt)
                            acc[mt][nt] = __builtin_amdgcn_mfma_f32_16x16x32_f16(
                                a, b[nt], acc[mt][nt], 0, 0, 0);
                    }
                }
            }
        }
    }

    // epilogue: scale+bias+relu; D layout: co=l16(+nt*16), px=mt*16+quad*4+reg
    const int h = h0 + wave;
#pragma unroll
    for (int nt = 0; nt < 4; ++nt) {
        const int co = nt * 16 + l16;
        const float s = scale[co];
        const float bb = bias[co];
#pragma unroll
        for (int mt = 0; mt < 3; ++mt) {
            const int w0 = wb + mt * 16 + quad * 4;  // multiple of 4
            if (w0 < WW) {
                if (FINAL) {
                    f4 v;
#pragma unroll
                    for (int r = 0; r < 4; ++r) {
                        float x = acc[mt][nt][r] * s + bb;
                        v[r] = x > 0.f ? x : 0.f;
                    }
                    *(f4*)((float*)outp + (((size_t)(co * 2 + d)) * HH + h) * WW + w0) = v;
                } else {
#pragma unroll
                    for (int r = 0; r < 4; ++r) {
                        float x = acc[mt][nt][r] * s + bb;
                        x = x > 0.f ? x : 0.f;
                        const int P = w0 + r + 1;
                        const int swz = (((co >> 3) ^ (P & 7)) << 3) | (co & 7);
                        ((_Float16*)outp)[(size_t)d * SLICE +
                            ((size_t)(h + 1) * WP + P) * 64 + swz] = (_Float16)x;
                    }
                }
            }
        }
    }
}

// ---------------- launch ---------------------------------------------------
extern "C" void kernel_launch(void* const* d_in, const int* in_sizes, int n_in,
                              void* d_out, int out_size, void* d_ws, size_t ws_size,
                              hipStream_t stream) {
    const float* feat   = (const float*)d_in[0];
    const int*   coors  = (const int*)d_in[1];
    const float* W1     = (const float*)d_in[3];
    const float* scale1 = (const float*)d_in[4];
    const float* bias1  = (const float*)d_in[5];
    const float* W2     = (const float*)d_in[6];
    const float* scale2 = (const float*)d_in[7];
    const float* bias2  = (const float*)d_in[8];
    const float* W3     = (const float*)d_in[9];
    const float* scale3 = (const float*)d_in[10];
    const float* bias3  = (const float*)d_in[11];
    const int nvox = in_sizes[0] / 64;

    // workspace: [A1][win][A2][A3][wt1|wt2|wt3]; memset covers A1+win only
    const size_t nA1 = (size_t)D_IN * SLICE;     // fp16 elems
    const size_t nWin = (size_t)D_IN * HH * WW;  // ints
    const size_t nA2 = (size_t)D1 * SLICE;
    const size_t nA3 = (size_t)D2 * SLICE;
    const size_t nWT = (size_t)27 * 64 * 64;     // fp16 elems per set

    _Float16* A1 = (_Float16*)d_ws;
    int* win = (int*)(A1 + nA1);
    _Float16* A2 = (_Float16*)(win + nWin);
    _Float16* A3 = A2 + nA2;
    _Float16* wt1 = A3 + nA3;
    _Float16* wt2 = wt1 + nWT;
    _Float16* wt3 = wt2 + nWT;

    hipMemsetAsync(d_ws, 0, nA1 * sizeof(_Float16) + nWin * sizeof(int), stream);
    halo_k<<<dim3(D1 + D2), 256, 0, stream>>>(A2, A3);

    const int nwt_blk = (3 * 27 * 64 * 64 + 255) / 256;
    wtrans_k<<<nwt_blk, 256, 0, stream>>>(W1, W2, W3, wt1);

    winner_k<<<(nvox + 255) / 256, 256, 0, stream>>>(coors, win, nvox);
    scatter_k<<<(nvox + 3) / 4, 256, 0, stream>>>(feat, coors, win, A1, nvox);

    dim3 blk(256);
    // conv1: A1(10) -> A2(5)  (1000 blocks, 2/CU)
    conv_mfma_k<0><<<dim3(4, 50, D1), blk, 0, stream>>>(A1, A2, wt1, scale1, bias1, D_IN, 2, 1);
    // conv2: A2(5) -> A3(3)   (600 blocks)
    conv_mfma_k<0><<<dim3(4, 50, D2), blk, 0, stream>>>(A2, A3, wt2, scale2, bias2, D1, 1, 0);
    // conv3: A3(3) -> out planar fp32 (float4 stores)  (400 blocks)
    conv_mfma_k<1><<<dim3(4, 50, D3), blk, 0, stream>>>(A3, (float*)d_out, wt3, scale3, bias3, D2, 2, 1);
}